// Round 9
// baseline (109.448 us; speedup 1.0000x reference)
//
#include <hip/hip_runtime.h>
#include <hip/hip_bf16.h>

typedef unsigned short u16;
typedef __bf16 bf16x8 __attribute__((ext_vector_type(8)));
typedef float  f32x4  __attribute__((ext_vector_type(4)));

#define BB    4
#define SS    4096
#define DD    1024
#define EE    8
#define M_TOT (BB*SS)   /* 16384 */
#define N_TOT DD        /* 1024  */
#define K_TOT DD        /* 1024  */

#define BM 256
#define BN 128
#define BK2 32          /* K-subtile */
#define NSUB (K_TOT/BK2) /* 32 subtiles */

#define GATE_BLOCKS 1024   /* 16 tokens per block, 4 per wave */

__device__ __forceinline__ u16 f2bf(float f) {
  unsigned u = __builtin_bit_cast(unsigned, f);
  u += 0x7fffu + ((u >> 16) & 1u);          // round-to-nearest-even
  return (u16)(u >> 16);
}

__device__ __forceinline__ void stage16(u16* lds, const u16* g) {
  __builtin_amdgcn_global_load_lds((const __attribute__((address_space(1))) void*)g,
                                   (__attribute__((address_space(3))) void*)lds,
                                   16, 0, 0);
}

// ---------------------------------------------------------------------------
// Kernel 1: gate (fp32, exact) + token f32->bf16 convert, plus weight convert.
// (unchanged — measured ~92% of achievable HBM BW)
// ---------------------------------------------------------------------------
__global__ __launch_bounds__(256) void gate_convert_kernel(
    const float* __restrict__ tokens, const float* __restrict__ gate_w,
    const float* __restrict__ w0,     const float* __restrict__ w1,
    u16* __restrict__ tok_bf, u16* __restrict__ w0_bf, u16* __restrict__ w1_bf,
    float* __restrict__ scales)
{
  const int bid = blockIdx.x;
  const int tid = threadIdx.x;

  if (bid < GATE_BLOCKS) {
    __shared__ float gwT[EE][DD];       // 32 KB, transposed gate weights
    #pragma unroll
    for (int r = 0; r < 4; ++r) {
      const int d = r * 256 + tid;      // coalesced: lanes 32B apart
      float4 a = *(const float4*)&gate_w[d * EE];
      float4 b = *(const float4*)&gate_w[d * EE + 4];
      gwT[0][d] = a.x; gwT[1][d] = a.y; gwT[2][d] = a.z; gwT[3][d] = a.w;
      gwT[4][d] = b.x; gwT[5][d] = b.y; gwT[6][d] = b.z; gwT[7][d] = b.w;
    }
    __syncthreads();

    const int lane = tid & 63, wid = tid >> 6;
    const int tbase = (bid * 4 + wid) * 4;          // 4 tokens per wave

    float lg[4][EE];
    #pragma unroll
    for (int t = 0; t < 4; ++t)
      #pragma unroll
      for (int e = 0; e < EE; ++e) lg[t][e] = 0.0f;

    #pragma unroll
    for (int c = 0; c < 4; ++c) {
      const int d = c * 256 + lane * 4;
      float4 gw[EE];
      #pragma unroll
      for (int e = 0; e < EE; ++e)
        gw[e] = *(const float4*)&gwT[e][d];         // ds_read_b128, lanes 16B apart
      #pragma unroll
      for (int t = 0; t < 4; ++t) {
        const size_t off = (size_t)(tbase + t) * DD + d;
        float4 v = *(const float4*)(tokens + off);
        *(ushort4*)(tok_bf + off) =
            make_ushort4(f2bf(v.x), f2bf(v.y), f2bf(v.z), f2bf(v.w));
        #pragma unroll
        for (int e = 0; e < EE; ++e)
          lg[t][e] = fmaf(v.w, gw[e].w, fmaf(v.z, gw[e].z,
                     fmaf(v.y, gw[e].y, fmaf(v.x, gw[e].x, lg[t][e]))));
      }
    }

    // Expert-splitting butterfly reduce, then shuffle softmax/top-2.
    const int b0 = lane & 1, b1 = (lane >> 1) & 1, b2 = (lane >> 2) & 1;
    const int E  = b0 * 4 + (lane & 2) + b2;

    #pragma unroll
    for (int t = 0; t < 4; ++t) {
      float n0[4], n1[2], rr;
      #pragma unroll
      for (int i = 0; i < 4; ++i) {
        float send = b0 ? lg[t][i] : lg[t][i + 4];
        float keep = b0 ? lg[t][i + 4] : lg[t][i];
        n0[i] = keep + __shfl_xor(send, 1, 64);
      }
      #pragma unroll
      for (int i = 0; i < 2; ++i) {
        float send = b1 ? n0[i] : n0[i + 2];
        float keep = b1 ? n0[i + 2] : n0[i];
        n1[i] = keep + __shfl_xor(send, 2, 64);
      }
      {
        float send = b2 ? n1[0] : n1[1];
        float keep = b2 ? n1[1] : n1[0];
        rr = keep + __shfl_xor(send, 4, 64);
      }
      rr += __shfl_xor(rr, 8, 64);
      rr += __shfl_xor(rr, 16, 64);
      rr += __shfl_xor(rr, 32, 64);

      float m = rr;
      m = fmaxf(m, __shfl_xor(m, 1, 64));
      m = fmaxf(m, __shfl_xor(m, 2, 64));
      m = fmaxf(m, __shfl_xor(m, 4, 64));
      float p = __expf(rr - m);
      float s = p;
      s += __shfl_xor(s, 1, 64);
      s += __shfl_xor(s, 2, 64);
      s += __shfl_xor(s, 4, 64);

      int cnt = 0;
      #pragma unroll
      for (int k = 1; k < 8; ++k) {
        float Lo = __shfl_xor(rr, k, 64);
        const int Eo = E ^ ((k & 1) * 4 + (k & 2) + ((k >> 2) & 1));
        cnt += (Lo > rr || (Lo == rr && Eo < E)) ? 1 : 0;
      }
      if (lane < 8) {
        const float w = p / s;
        if (E == 0) scales[(tbase + t) * 2 + 0] = (cnt == 0) ? w : 0.0f;
        if (E == 1) scales[(tbase + t) * 2 + 1] = (cnt == 1) ? w : 0.0f;
      }
    }
  } else {
    const int wb = bid - GATE_BLOCKS;            // 0..2047
    const float* src = (wb < 1024) ? w0 : w1;
    u16*        dst = (wb < 1024) ? w0_bf : w1_bf;
    const int base = (wb & 1023) * 1024 + tid * 4;
    float4 v = *(const float4*)(src + base);
    *(ushort4*)(dst + base) =
        make_ushort4(f2bf(v.x), f2bf(v.y), f2bf(v.z), f2bf(v.w));
  }
}

// ---------------------------------------------------------------------------
// Kernel 2: fused dual-GEMM, v4: BK=32 subtiles, 4-buffer LDS rotation
// (static indices), prefetch distance 3 for staging, distance 1 for
// fragments.  Every MFMA batch's operands were ds_read a FULL SUBTILE
// earlier -> lgkm pre-satisfied; every vmcnt drains loads issued ~1500 cyc
// earlier -> free.  This breaks the measured read<->MFMA serialization
// (r8: 2304 cyc LDS reads + 2483 cyc MFMA strictly additive per tile).
// Per subtile: {batch1 | read B1 JIT | prefetch next A/B0 | stage t+3 |
// batch2 | vmcnt(4) | BAR}.  One barrier per subtile.
// Swizzle (r5-verified, 0 conflicts at BK=32): source chunk
// (tid&3)^((tid>>3)&3), read chunk fq^((fr>>1)&3).
// ---------------------------------------------------------------------------
__global__ __launch_bounds__(512, 2) void moe_gemm_kernel(
    const u16* __restrict__ A,    // [M,K] bf16
    const u16* __restrict__ Bw0,  // [N,K] bf16 (w0 row-major = B^T)
    const u16* __restrict__ Bw1,  // [N,K] bf16
    const float* __restrict__ bias0, const float* __restrict__ bias1,
    const float* __restrict__ scales, // [M,2]
    float* __restrict__ out)      // [M,N] f32
{
  __shared__ u16 lA [4][BM * BK2];   // 4 x 16 KiB
  __shared__ u16 lB0[4][BN * BK2];   // 4 x  8 KiB
  __shared__ u16 lB1[4][BN * BK2];   // 4 x  8 KiB  -> 128 KiB total

  const int tid = threadIdx.x;

  // bijective XCD swizzle: 512 blocks, 8 XCDs, 64 blocks/XCD chunk.
  const int wgid = (blockIdx.x & 7) * 64 + (blockIdx.x >> 3);
  const int bm = wgid >> 3, bn = wgid & 7;    // bn fastest: XCD shares A panels
  const int m0 = bm * BM, n0 = bn * BN;

  const int lane = tid & 63;
  const int wid  = tid >> 6;                  // 0..7
  const int wm = wid >> 1, wn = wid & 1;      // 4M x 2N wave grid
  const int fr = lane & 15, fq = lane >> 4;
  const int frh = (fr >> 1) & 3;              // read-swizzle term (BK=32)

  // staging: row = tid>>2 (0..127), phys chunk = tid&3; inverse-swizzled src.
  const int schunk = ((tid & 3) ^ ((tid >> 3) & 3)) * 8;
  const u16* gA  = A   + (size_t)(m0 + (tid >> 2)) * K_TOT + schunk;
  const u16* gA2 = gA  + (size_t)128 * K_TOT;
  const u16* gB0 = Bw0 + (size_t)(n0 + (tid >> 2)) * K_TOT + schunk;
  const u16* gB1 = Bw1 + (size_t)(n0 + (tid >> 2)) * K_TOT + schunk;

#define STAGE_SUB(B, KO) do {                              \
    stage16(&lA [B][tid * 8],        gA  + (KO));          \
    stage16(&lA [B][4096 + tid * 8], gA2 + (KO));          \
    stage16(&lB0[B][tid * 8],        gB0 + (KO));          \
    stage16(&lB1[B][tid * 8],        gB1 + (KO));          \
  } while (0)

#define FRAGX(L, rowbase) \
  (*(const bf16x8*)&L[((rowbase) + fr) * BK2 + (fq ^ frh) * 8])

#define BAR()        __builtin_amdgcn_s_barrier()
#define WAIT_VM(N)   asm volatile("s_waitcnt vmcnt(" #N ")" ::: "memory")
#define NO_WAIT      ((void)0)

#define BATCH(ACC, AF, BF) do {                                               \
    __builtin_amdgcn_s_setprio(1);                                            \
    _Pragma("unroll")                                                         \
    for (int i = 0; i < 4; ++i)                                               \
      _Pragma("unroll")                                                       \
      for (int j = 0; j < 4; ++j)                                             \
        ACC[i][j] = __builtin_amdgcn_mfma_f32_16x16x32_bf16(AF[i], BF[j],     \
                                                            ACC[i][j], 0,0,0);\
    __builtin_amdgcn_s_setprio(0);                                            \
  } while (0)

  // Subtile body.  BC/BN_ = current/next buffer (compile-time).  AFC/BFC =
  // current frag bank (read during previous subtile); AFN/BFN = bank to
  // prefetch into.  STG: stage subtile (s+3) at K-offset KO3.  WN: wait.
#define SUBT(BC, BN_, AFC, BFC, AFN, BFN, STG, SB, KO3, WN, DOBAR) do {       \
    BATCH(acc0, AFC, BFC);                      /* operands pre-read: no wait */ \
    _Pragma("unroll")                                                         \
    for (int j = 0; j < 4; ++j) bB[j] = FRAGX(lB1[BC], wn * 64 + j * 16);     \
    _Pragma("unroll")                                                         \
    for (int i = 0; i < 4; ++i) AFN[i] = FRAGX(lA[BN_], wm * 64 + i * 16);    \
    _Pragma("unroll")                                                         \
    for (int j = 0; j < 4; ++j) BFN[j] = FRAGX(lB0[BN_], wn * 64 + j * 16);   \
    if (STG) STAGE_SUB(SB, KO3);                                              \
    BATCH(acc1, AFC, bB);                       /* waits only bB (counted) */ \
    WN;                                                                       \
    if (DOBAR) BAR();                                                         \
  } while (0)

  f32x4 acc0[4][4] = {};
  f32x4 acc1[4][4] = {};
  bf16x8 afA[4], bA[4], afB[4], bBn[4], bB[4];   // named banks (rule 20)

  // Prologue: stage subtiles 0,1,2; drain 0+1 (leave 2 in flight); barrier;
  // pre-read subtile-0 fragments.
  STAGE_SUB(0, 0);
  STAGE_SUB(1, BK2);
  STAGE_SUB(2, 2 * BK2);
  WAIT_VM(4);
  BAR();
  #pragma unroll
  for (int i = 0; i < 4; ++i) afA[i] = FRAGX(lA[0], wm * 64 + i * 16);
  #pragma unroll
  for (int j = 0; j < 4; ++j) bA[j]  = FRAGX(lB0[0], wn * 64 + j * 16);

  // Steady: subtiles 0..27 (7 iterations x 4, static buffers + bank ping-pong).
  for (int it = 0; it < 7; ++it) {
    const int ko = it * 4 * BK2;
    SUBT(0, 1, afA, bA,  afB, bBn, 1, 3, ko + 3 * BK2, WAIT_VM(4), 1);
    SUBT(1, 2, afB, bBn, afA, bA,  1, 0, ko + 4 * BK2, WAIT_VM(4), 1);
    SUBT(2, 3, afA, bA,  afB, bBn, 1, 1, ko + 5 * BK2, WAIT_VM(4), 1);
    SUBT(3, 0, afB, bBn, afA, bA,  1, 2, ko + 6 * BK2, WAIT_VM(4), 1);
  }

  // Tail: subtiles 28..31.
  SUBT(0, 1, afA, bA,  afB, bBn, 1, 3, 31 * BK2, WAIT_VM(4), 1);  // s28
  SUBT(1, 2, afB, bBn, afA, bA,  0, 0, 0,        WAIT_VM(0), 1);  // s29
  SUBT(2, 3, afA, bA,  afB, bBn, 0, 0, 0,        NO_WAIT,    0);  // s30
  {                                                               // s31
    BATCH(acc0, afB, bBn);
    #pragma unroll
    for (int j = 0; j < 4; ++j) bB[j] = FRAGX(lB1[3], wn * 64 + j * 16);
    BATCH(acc1, afB, bB);
  }

  // Epilogue: out = s0*silu(acc0+b0) + s1*silu(acc1+b1)
  float bb0[4], bb1[4];
  #pragma unroll
  for (int j = 0; j < 4; ++j) {
    const int col = n0 + wn * 64 + j * 16 + fr;
    bb0[j] = bias0[col];
    bb1[j] = bias1[col];
  }
  #pragma unroll
  for (int i = 0; i < 4; ++i) {
    #pragma unroll
    for (int r = 0; r < 4; ++r) {
      const int grow = m0 + wm * 64 + i * 16 + fq * 4 + r;  // C row=(lane>>4)*4+reg
      const float s0 = scales[grow * 2 + 0];
      const float s1 = scales[grow * 2 + 1];
      float* orow = out + (size_t)grow * N_TOT + n0 + wn * 64;
      #pragma unroll
      for (int j = 0; j < 4; ++j) {
        const float v0 = acc0[i][j][r] + bb0[j];
        const float v1 = acc1[i][j][r] + bb1[j];
        const float g0 = v0 / (1.0f + __expf(-v0));
        const float g1 = v1 / (1.0f + __expf(-v1));
        orow[j * 16 + fr] = s0 * g0 + s1 * g1;              // col = lane&15
      }
    }
  }
#undef STAGE_SUB
#undef FRAGX
#undef BAR
#undef WAIT_VM
#undef NO_WAIT
#undef BATCH
#undef SUBT
}

// ---------------------------------------------------------------------------
extern "C" void kernel_launch(void* const* d_in, const int* in_sizes, int n_in,
                              void* d_out, int out_size, void* d_ws, size_t ws_size,
                              hipStream_t stream)
{
  const float* tokens = (const float*)d_in[0];
  const float* gate_w = (const float*)d_in[1];
  const float* w0     = (const float*)d_in[2];
  const float* b0     = (const float*)d_in[3];
  const float* w1     = (const float*)d_in[4];
  const float* b1     = (const float*)d_in[5];
  float* out = (float*)d_out;

  char* ws = (char*)d_ws;
  u16* tok_bf = (u16*)ws;                                               // 32 MB
  u16* w0_bf  = (u16*)(ws + (size_t)M_TOT * K_TOT * 2);                 //  2 MB
  u16* w1_bf  = (u16*)(ws + (size_t)M_TOT * K_TOT * 2 + (size_t)N_TOT * K_TOT * 2);
  float* scales = (float*)(ws + (size_t)M_TOT * K_TOT * 2 + (size_t)2 * N_TOT * K_TOT * 2);

  gate_convert_kernel<<<GATE_BLOCKS + 2048, 256, 0, stream>>>(
      tokens, gate_w, w0, w1, tok_bf, w0_bf, w1_bf, scales);

  moe_gemm_kernel<<<(M_TOT/BM) * (N_TOT/BN), 512, 0, stream>>>(
      tok_bf, w0_bf, w1_bf, b0, b1, scales, out);
}

// Round 10
// 103.695 us; speedup vs baseline: 1.0555x; 1.0555x over previous
//
#include <hip/hip_runtime.h>
#include <hip/hip_bf16.h>

typedef unsigned short u16;
typedef __bf16 bf16x8 __attribute__((ext_vector_type(8)));
typedef float  f32x4  __attribute__((ext_vector_type(4)));

#define BB    4
#define SS    4096
#define DD    1024
#define EE    8
#define M_TOT (BB*SS)   /* 16384 */
#define N_TOT DD        /* 1024  */
#define K_TOT DD        /* 1024  */

#define BM 256
#define BN 128
#define BK 64
#define NT (K_TOT/BK)   /* 16 K-tiles */

#define GATE_BLOCKS 1024   /* 16 tokens per block, 4 per wave */

__device__ __forceinline__ u16 f2bf(float f) {
  unsigned u = __builtin_bit_cast(unsigned, f);
  u += 0x7fffu + ((u >> 16) & 1u);          // round-to-nearest-even
  return (u16)(u >> 16);
}

__device__ __forceinline__ void stage16(u16* lds, const u16* g) {
  __builtin_amdgcn_global_load_lds((const __attribute__((address_space(1))) void*)g,
                                   (__attribute__((address_space(3))) void*)lds,
                                   16, 0, 0);
}

// ---------------------------------------------------------------------------
// Kernel 1: gate (fp32, exact) + token f32->bf16 convert, plus weight convert.
// (unchanged — measured ~92% of achievable HBM BW)
// ---------------------------------------------------------------------------
__global__ __launch_bounds__(256) void gate_convert_kernel(
    const float* __restrict__ tokens, const float* __restrict__ gate_w,
    const float* __restrict__ w0,     const float* __restrict__ w1,
    u16* __restrict__ tok_bf, u16* __restrict__ w0_bf, u16* __restrict__ w1_bf,
    float* __restrict__ scales)
{
  const int bid = blockIdx.x;
  const int tid = threadIdx.x;

  if (bid < GATE_BLOCKS) {
    __shared__ float gwT[EE][DD];       // 32 KB, transposed gate weights
    #pragma unroll
    for (int r = 0; r < 4; ++r) {
      const int d = r * 256 + tid;      // coalesced: lanes 32B apart
      float4 a = *(const float4*)&gate_w[d * EE];
      float4 b = *(const float4*)&gate_w[d * EE + 4];
      gwT[0][d] = a.x; gwT[1][d] = a.y; gwT[2][d] = a.z; gwT[3][d] = a.w;
      gwT[4][d] = b.x; gwT[5][d] = b.y; gwT[6][d] = b.z; gwT[7][d] = b.w;
    }
    __syncthreads();

    const int lane = tid & 63, wid = tid >> 6;
    const int tbase = (bid * 4 + wid) * 4;          // 4 tokens per wave

    float lg[4][EE];
    #pragma unroll
    for (int t = 0; t < 4; ++t)
      #pragma unroll
      for (int e = 0; e < EE; ++e) lg[t][e] = 0.0f;

    #pragma unroll
    for (int c = 0; c < 4; ++c) {
      const int d = c * 256 + lane * 4;
      float4 gw[EE];
      #pragma unroll
      for (int e = 0; e < EE; ++e)
        gw[e] = *(const float4*)&gwT[e][d];         // ds_read_b128, lanes 16B apart
      #pragma unroll
      for (int t = 0; t < 4; ++t) {
        const size_t off = (size_t)(tbase + t) * DD + d;
        float4 v = *(const float4*)(tokens + off);
        *(ushort4*)(tok_bf + off) =
            make_ushort4(f2bf(v.x), f2bf(v.y), f2bf(v.z), f2bf(v.w));
        #pragma unroll
        for (int e = 0; e < EE; ++e)
          lg[t][e] = fmaf(v.w, gw[e].w, fmaf(v.z, gw[e].z,
                     fmaf(v.y, gw[e].y, fmaf(v.x, gw[e].x, lg[t][e]))));
      }
    }

    // Expert-splitting butterfly reduce, then shuffle softmax/top-2.
    const int b0 = lane & 1, b1 = (lane >> 1) & 1, b2 = (lane >> 2) & 1;
    const int E  = b0 * 4 + (lane & 2) + b2;

    #pragma unroll
    for (int t = 0; t < 4; ++t) {
      float n0[4], n1[2], rr;
      #pragma unroll
      for (int i = 0; i < 4; ++i) {
        float send = b0 ? lg[t][i] : lg[t][i + 4];
        float keep = b0 ? lg[t][i + 4] : lg[t][i];
        n0[i] = keep + __shfl_xor(send, 1, 64);
      }
      #pragma unroll
      for (int i = 0; i < 2; ++i) {
        float send = b1 ? n0[i] : n0[i + 2];
        float keep = b1 ? n0[i + 2] : n0[i];
        n1[i] = keep + __shfl_xor(send, 2, 64);
      }
      {
        float send = b2 ? n1[0] : n1[1];
        float keep = b2 ? n1[1] : n1[0];
        rr = keep + __shfl_xor(send, 4, 64);
      }
      rr += __shfl_xor(rr, 8, 64);
      rr += __shfl_xor(rr, 16, 64);
      rr += __shfl_xor(rr, 32, 64);

      float m = rr;
      m = fmaxf(m, __shfl_xor(m, 1, 64));
      m = fmaxf(m, __shfl_xor(m, 2, 64));
      m = fmaxf(m, __shfl_xor(m, 4, 64));
      float p = __expf(rr - m);
      float s = p;
      s += __shfl_xor(s, 1, 64);
      s += __shfl_xor(s, 2, 64);
      s += __shfl_xor(s, 4, 64);

      int cnt = 0;
      #pragma unroll
      for (int k = 1; k < 8; ++k) {
        float Lo = __shfl_xor(rr, k, 64);
        const int Eo = E ^ ((k & 1) * 4 + (k & 2) + ((k >> 2) & 1));
        cnt += (Lo > rr || (Lo == rr && Eo < E)) ? 1 : 0;
      }
      if (lane < 8) {
        const float w = p / s;
        if (E == 0) scales[(tbase + t) * 2 + 0] = (cnt == 0) ? w : 0.0f;
        if (E == 1) scales[(tbase + t) * 2 + 1] = (cnt == 1) ? w : 0.0f;
      }
    }
  } else {
    const int wb = bid - GATE_BLOCKS;            // 0..2047
    const float* src = (wb < 1024) ? w0 : w1;
    u16*        dst = (wb < 1024) ? w0_bf : w1_bf;
    const int base = (wb & 1023) * 1024 + tid * 4;
    float4 v = *(const float4*)(src + base);
    *(ushort4*)(dst + base) =
        make_ushort4(f2bf(v.x), f2bf(v.y), f2bf(v.z), f2bf(v.w));
  }
}

// ---------------------------------------------------------------------------
// Kernel 2: fused dual-GEMM, v5: exact m201-template phase structure.
// BM=256 x BN=128, BK=64, 8 waves (4M x 2N), 128 KiB LDS double-buffer.
// Per K-tile, 4 phases; each phase:
//   { in-phase ds_reads (compiler-visible, counted waits)
//     2 x global_load_lds stage (staggered 2/phase)
//     BAR();  asm lgkmcnt(0) WITHOUT sched_barrier  <- r6's pin was the convoy
//     setprio(1); 16 MFMA; setprio(0); [counted vmcnt]; BAR(); }
// vmcnt: vm(2) at p0-end (drains old B1, leaves new A' x2 in flight) and
// p3-end (drains A'+B0', leaves B1' in flight).  Never 0 in steady loop.
// Swizzle (r5-verified 0-conflict): dest linear, src chunk (tid&7)^((tid>>4)&7),
// read chunk ((kk<<2)|fq)^(fr>>1).
// ---------------------------------------------------------------------------
__global__ __launch_bounds__(512, 2) void moe_gemm_kernel(
    const u16* __restrict__ A,    // [M,K] bf16
    const u16* __restrict__ Bw0,  // [N,K] bf16 (w0 row-major = B^T)
    const u16* __restrict__ Bw1,  // [N,K] bf16
    const float* __restrict__ bias0, const float* __restrict__ bias1,
    const float* __restrict__ scales, // [M,2]
    float* __restrict__ out)      // [M,N] f32
{
  __shared__ u16 lA [2][BM * BK];   // 64 KiB
  __shared__ u16 lB0[2][BN * BK];   // 32 KiB
  __shared__ u16 lB1[2][BN * BK];   // 32 KiB

  const int tid = threadIdx.x;

  // bijective XCD swizzle: 512 blocks, 8 XCDs, 64 blocks/XCD chunk.
  const int wgid = (blockIdx.x & 7) * 64 + (blockIdx.x >> 3);
  const int bm = wgid >> 3, bn = wgid & 7;    // bn fastest: XCD shares A panels
  const int m0 = bm * BM, n0 = bn * BN;

  const int lane = tid & 63;
  const int wid  = tid >> 6;                  // 0..7
  const int wm = wid >> 1, wn = wid & 1;      // 4M x 2N wave grid
  const int fr = lane & 15, fq = lane >> 4;
  const int frh = fr >> 1;                    // read-swizzle term

  const int schunk = ((tid & 7) ^ ((tid >> 4) & 7)) * 8;
  const u16* gA  = A   + (size_t)(m0 + (tid >> 3)) * K_TOT + schunk;
  const u16* gB0 = Bw0 + (size_t)(n0 + (tid >> 3)) * K_TOT + schunk;
  const u16* gB1 = Bw1 + (size_t)(n0 + (tid >> 3)) * K_TOT + schunk;

#define STAGE_A(buf, c, ko)  stage16(&lA [buf][(c)*4096 + tid*8], gA  + (size_t)(c)*64*K_TOT + (ko))
#define STAGE_B0(buf, c, ko) stage16(&lB0[buf][(c)*4096 + tid*8], gB0 + (size_t)(c)*64*K_TOT + (ko))
#define STAGE_B1(buf, c, ko) stage16(&lB1[buf][(c)*4096 + tid*8], gB1 + (size_t)(c)*64*K_TOT + (ko))

#define FRAG(L, buf, rowbase, kk) \
  (*(const bf16x8*)&L[buf][((rowbase) + fr) * BK + ((((kk) << 2) | fq) ^ frh) * 8])

#define BAR()        __builtin_amdgcn_s_barrier()
#define LGKM0()      asm volatile("s_waitcnt lgkmcnt(0)" ::: "memory")
#define WAIT_VM(N)   asm volatile("s_waitcnt vmcnt(" #N ")" ::: "memory")

#define MFMA16(ACC, AF, BF) do {                                              \
    __builtin_amdgcn_s_setprio(1);                                            \
    _Pragma("unroll")                                                         \
    for (int i = 0; i < 4; ++i)                                               \
      _Pragma("unroll")                                                       \
      for (int j = 0; j < 4; ++j)                                             \
        ACC[i][j] = __builtin_amdgcn_mfma_f32_16x16x32_bf16(AF[i], BF[j],     \
                                                            ACC[i][j], 0,0,0);\
    __builtin_amdgcn_s_setprio(0);                                            \
  } while (0)

  f32x4 acc0[4][4] = {};
  f32x4 acc1[4][4] = {};
  bf16x8 afA[4], afB[4], bfr[4];   // 3 named frag banks (rule 20)

  // Prologue: stage K-tile 0 (FIFO: A x4, B0 x2, B1 x2); wait A+B0,
  // leave B1 in flight (steady-state invariant); barrier.
  STAGE_A(0, 0, 0); STAGE_A(0, 1, 0); STAGE_A(0, 2, 0); STAGE_A(0, 3, 0);
  STAGE_B0(0, 0, 0); STAGE_B0(0, 1, 0);
  STAGE_B1(0, 0, 0); STAGE_B1(0, 1, 0);
  WAIT_VM(2);
  BAR();

  int cur = 0;
  // Steady tiles 0..NT-2 (each prefetches tile t+1, 2 loads per phase).
  for (int t = 0; t < NT - 1; ++t) {
    const int nxt = cur ^ 1;
    const size_t ko = (size_t)(t + 1) * BK;

    // ---- p0: (e0, k0) ----
    #pragma unroll
    for (int i = 0; i < 4; ++i) afA[i] = FRAG(lA,  cur, wm * 64 + i * 16, 0);
    #pragma unroll
    for (int j = 0; j < 4; ++j) bfr[j] = FRAG(lB0, cur, wn * 64 + j * 16, 0);
    STAGE_A(nxt, 0, ko); STAGE_A(nxt, 1, ko);
    BAR(); LGKM0();
    MFMA16(acc0, afA, bfr);
    WAIT_VM(2);                 // drains old B1[cur]; 2 new A' stay in flight
    BAR();

    // ---- p1: (e1, k0), A k0-frags reused ----
    #pragma unroll
    for (int j = 0; j < 4; ++j) bfr[j] = FRAG(lB1, cur, wn * 64 + j * 16, 0);
    STAGE_A(nxt, 2, ko); STAGE_A(nxt, 3, ko);
    BAR(); LGKM0();
    MFMA16(acc1, afA, bfr);
    BAR();

    // ---- p2: (e0, k1) ----
    #pragma unroll
    for (int i = 0; i < 4; ++i) afB[i] = FRAG(lA,  cur, wm * 64 + i * 16, 1);
    #pragma unroll
    for (int j = 0; j < 4; ++j) bfr[j] = FRAG(lB0, cur, wn * 64 + j * 16, 1);
    STAGE_B0(nxt, 0, ko); STAGE_B0(nxt, 1, ko);
    BAR(); LGKM0();
    MFMA16(acc0, afB, bfr);
    BAR();

    // ---- p3: (e1, k1) ----
    #pragma unroll
    for (int j = 0; j < 4; ++j) bfr[j] = FRAG(lB1, cur, wn * 64 + j * 16, 1);
    STAGE_B1(nxt, 0, ko); STAGE_B1(nxt, 1, ko);
    BAR(); LGKM0();
    MFMA16(acc1, afB, bfr);
    WAIT_VM(2);                 // drains A'+B0'; B1' stays in flight
    BAR();

    cur = nxt;
  }

  // Peeled last tile (no prefetch).
  {
    // p0
    #pragma unroll
    for (int i = 0; i < 4; ++i) afA[i] = FRAG(lA,  cur, wm * 64 + i * 16, 0);
    #pragma unroll
    for (int j = 0; j < 4; ++j) bfr[j] = FRAG(lB0, cur, wn * 64 + j * 16, 0);
    BAR(); LGKM0();
    MFMA16(acc0, afA, bfr);
    WAIT_VM(0);                 // drain last B1
    BAR();
    // p1
    #pragma unroll
    for (int j = 0; j < 4; ++j) bfr[j] = FRAG(lB1, cur, wn * 64 + j * 16, 0);
    BAR(); LGKM0();
    MFMA16(acc1, afA, bfr);
    BAR();
    // p2
    #pragma unroll
    for (int i = 0; i < 4; ++i) afB[i] = FRAG(lA,  cur, wm * 64 + i * 16, 1);
    #pragma unroll
    for (int j = 0; j < 4; ++j) bfr[j] = FRAG(lB0, cur, wn * 64 + j * 16, 1);
    BAR(); LGKM0();
    MFMA16(acc0, afB, bfr);
    BAR();
    // p3
    #pragma unroll
    for (int j = 0; j < 4; ++j) bfr[j] = FRAG(lB1, cur, wn * 64 + j * 16, 1);
    LGKM0();
    MFMA16(acc1, afB, bfr);
  }

  // Epilogue: out = s0*silu(acc0+b0) + s1*silu(acc1+b1)
  float bb0[4], bb1[4];
  #pragma unroll
  for (int j = 0; j < 4; ++j) {
    const int col = n0 + wn * 64 + j * 16 + fr;
    bb0[j] = bias0[col];
    bb1[j] = bias1[col];
  }
  #pragma unroll
  for (int i = 0; i < 4; ++i) {
    #pragma unroll
    for (int r = 0; r < 4; ++r) {
      const int grow = m0 + wm * 64 + i * 16 + fq * 4 + r;  // C row=(lane>>4)*4+reg
      const float s0 = scales[grow * 2 + 0];
      const float s1 = scales[grow * 2 + 1];
      float* orow = out + (size_t)grow * N_TOT + n0 + wn * 64;
      #pragma unroll
      for (int j = 0; j < 4; ++j) {
        const float v0 = acc0[i][j][r] + bb0[j];
        const float v1 = acc1[i][j][r] + bb1[j];
        const float g0 = v0 / (1.0f + __expf(-v0));
        const float g1 = v1 / (1.0f + __expf(-v1));
        orow[j * 16 + fr] = s0 * g0 + s1 * g1;              // col = lane&15
      }
    }
  }
#undef STAGE_A
#undef STAGE_B0
#undef STAGE_B1
#undef FRAG
#undef BAR
#undef LGKM0
#undef WAIT_VM
#undef MFMA16
}

// ---------------------------------------------------------------------------
extern "C" void kernel_launch(void* const* d_in, const int* in_sizes, int n_in,
                              void* d_out, int out_size, void* d_ws, size_t ws_size,
                              hipStream_t stream)
{
  const float* tokens = (const float*)d_in[0];
  const float* gate_w = (const float*)d_in[1];
  const float* w0     = (const float*)d_in[2];
  const float* b0     = (const float*)d_in[3];
  const float* w1     = (const float*)d_in[4];
  const float* b1     = (const float*)d_in[5];
  float* out = (float*)d_out;

  char* ws = (char*)d_ws;
  u16* tok_bf = (u16*)ws;                                               // 32 MB
  u16* w0_bf  = (u16*)(ws + (size_t)M_TOT * K_TOT * 2);                 //  2 MB
  u16* w1_bf  = (u16*)(ws + (size_t)M_TOT * K_TOT * 2 + (size_t)N_TOT * K_TOT * 2);
  float* scales = (float*)(ws + (size_t)M_TOT * K_TOT * 2 + (size_t)2 * N_TOT * K_TOT * 2);

  gate_convert_kernel<<<GATE_BLOCKS + 2048, 256, 0, stream>>>(
      tokens, gate_w, w0, w1, tok_bf, w0_bf, w1_bf, scales);

  moe_gemm_kernel<<<(M_TOT/BM) * (N_TOT/BN), 512, 0, stream>>>(
      tok_bf, w0_bf, w1_bf, b0, b1, scales, out);
}